// Round 9
// baseline (78.383 us; speedup 1.0000x reference)
//
#include <hip/hip_runtime.h>
#include <hip/hip_bf16.h>

// B=16, C=64, P=128, L=16, D=256, NPF=256, NRFF=128, FEAT=656
// ws layout (float slots):
#define WS_WK0   0        // 16     wk0 = Wk0^T q0
#define WS_A     16       // 256    A = Wq1^T Wk1
#define WS_E0    272      // 4096   E0 = Pp0 * Wv0  (256 x 16), f32 (for c0)
#define WS_BT    4368     // 20480 f32-slots = 40960 ushort: BTall[256][160] bf16
//   BTall[d][kk]: 0..15 Px; 16..31 E1; 32..95 Psin; 96..159 Pcos

// Acts slab for (b,p) lives in out rows c=0..20 (1 KB each), overwritten by gemm:
//   rows 0..19: bf16 acts [kt][c][8k]  (kt0-1=x, kt2-3=M, kt4-11=sin, kt12-19=cos)
//   row  20   : c0[256] f32
#define SLAB(b,p,kt) ((((b)*64 + (kt))*128 + (p)) << 8)   // float index into out

typedef float f32x4 __attribute__((ext_vector_type(4)));
typedef short s16x8 __attribute__((ext_vector_type(8)));
typedef short s16x4 __attribute__((ext_vector_type(4)));

static __device__ __forceinline__ short bf16b(float f) {
  __hip_bfloat16 h = __float2bfloat16(f);
  return __builtin_bit_cast(short, h);
}

// lgkmcnt-only barrier: orders LDS producer->consumer without draining vmcnt,
// so global stores / prefetches stay in flight across phases.
static __device__ __forceinline__ void bar_lds() {
  asm volatile("s_waitcnt lgkmcnt(0)\n\ts_barrier" ::: "memory");
}

__global__ __launch_bounds__(512)
void pre_kernel(const float* __restrict__ Wq, const float* __restrict__ Wk,
                const float* __restrict__ Wv, const float* __restrict__ pw,
                float* __restrict__ ws)
{
  __shared__ float lds[8704];   // [0..4095] m1^T, [4096..8191] m2^T, [8192..8447] q0, [8448..8703] partial
  const int t = threadIdx.x;
  const int blk = blockIdx.x;
  ushort* bt = (ushort*)(ws + WS_BT);

  if (blk == 0) {
    {
      const int d = t >> 1;
      const int lb = (t & 1) * 8;
      #pragma unroll
      for (int h = 0; h < 2; ++h) {
        const float4 vq = *(const float4*)(Wq + 4096 + t*8 + h*4);
        lds[(lb+h*4+0)*256 + d] = vq.x;
        lds[(lb+h*4+1)*256 + d] = vq.y;
        lds[(lb+h*4+2)*256 + d] = vq.z;
        lds[(lb+h*4+3)*256 + d] = vq.w;
        const float4 vk = *(const float4*)(Wk + 4096 + t*8 + h*4);
        lds[4096 + (lb+h*4+0)*256 + d] = vk.x;
        lds[4096 + (lb+h*4+1)*256 + d] = vk.y;
        lds[4096 + (lb+h*4+2)*256 + d] = vk.z;
        lds[4096 + (lb+h*4+3)*256 + d] = vk.w;
      }
    }
    if (t < 256) {
      float s = 0.f;
      #pragma unroll
      for (int q = 0; q < 4; ++q) {
        const float4 v = *(const float4*)(Wq + t*16 + q*4);
        s += v.x + v.y + v.z + v.w;           // q0[d]
      }
      lds[8192 + t] = s;
    }
    __syncthreads();
    if (t < 256) {
      const int l1 = t >> 4, l2 = t & 15;
      const float* r1 = lds + l1*256;
      const float* r2 = lds + 4096 + l2*256;
      float s = 0.f;
      #pragma unroll 8
      for (int dq = 0; dq < 64; ++dq) {
        const float4 a = *(const float4*)(r1 + dq*4);
        const float4 b = *(const float4*)(r2 + dq*4);
        s += a.x*b.x + a.y*b.y + a.z*b.z + a.w*b.w;    // A[l1,l2]
      }
      ws[WS_A + t] = s;
    }
    if (t < 256) {                 // wk0 partial sums, parallel over d-chunks
      const int l = t & 15, ch = t >> 4;
      float s = 0.f;
      #pragma unroll
      for (int i = 0; i < 16; ++i)
        s += lds[8192 + ch*16 + i] * Wk[(ch*16 + i)*16 + l];
      lds[8448 + t] = s;
    }
    __syncthreads();
    if (t < 16) {
      float s = 0.f;
      #pragma unroll
      for (int ch = 0; ch < 16; ++ch) s += lds[8448 + ch*16 + t];
      ws[WS_WK0 + t] = s;          // wk0[l]
    }
  } else if (blk <= 16) {
    const int deg = (blk <= 8) ? 0 : 1;
    {
      const int f = t >> 1;
      const int lb = (t & 1) * 8;
      #pragma unroll
      for (int h = 0; h < 2; ++h) {
        const float4 v = *(const float4*)(Wv + deg*4096 + t*8 + h*4);
        lds[(lb+h*4+0)*256 + f] = v.x;
        lds[(lb+h*4+1)*256 + f] = v.y;
        lds[(lb+h*4+2)*256 + f] = v.z;
        lds[(lb+h*4+3)*256 + f] = v.w;
      }
    }
    __syncthreads();
    const int d = ((blk-1) & 7)*32 + (t >> 4);
    const int l = t & 15;
    const float* pr = pw + d*656 + (deg ? 272 : 16);
    const float* wv = lds + l*256;
    float s = 0.f;
    #pragma unroll 8
    for (int fq = 0; fq < 64; ++fq) {
      const float4 a = *(const float4*)(pr + fq*4);
      const float4 b = *(const float4*)(wv + fq*4);
      s += a.x*b.x + a.y*b.y + a.z*b.z + a.w*b.w;
    }
    if (deg == 0) {
      ws[WS_E0 + d*16 + l] = s;
      bt[d*160 + l] = (ushort)bf16b(pw[d*656 + l]);
    } else {
      bt[d*160 + 16 + l] = (ushort)bf16b(s);
    }
  } else {
    #pragma unroll 4
    for (int k = 0; k < 64; ++k) {
      const int d = k*4 + (t >> 7);
      const int j = t & 127;
      const float v = (j < 64) ? pw[d*656 + 528 + j] : pw[d*656 + 592 + (j-64)];
      bt[d*160 + 32 + j] = (ushort)bf16b(v);
    }
  }
}

// ---------------- acts builder: per (b,p) write 20 bf16 rows + c0 ----------------
__global__ __launch_bounds__(256, 4)
void acts_kernel(const float* __restrict__ x, const float* __restrict__ fw,
                 const float* __restrict__ fb, const float* __restrict__ pb,
                 const float* __restrict__ ws, float* __restrict__ out)
{
  __shared__ float XsT[16*68];   // f32 x^T [l][c]
  __shared__ float fws[16*64];
  __shared__ float fbs[64];
  __shared__ float Gs[256];      // G = X^T X
  __shared__ float Ys[64*16];    // Y = X * A
  __shared__ float tls[16];      // G * wk0

  const int t = threadIdx.x;
  const int b = blockIdx.x >> 7;
  const int p = blockIdx.x & 127;
  const int xc = t >> 2, xl0 = (t & 3) * 4;

  // ---- P1: stage X (f32 LDS); bf16 x -> global rows 0-1; fw/fb -> LDS ----
  {
    const float4 v = *(const float4*)(x + (((b*64 + xc)*128 + p) << 4) + xl0);
    XsT[(xl0+0)*68 + xc] = v.x;
    XsT[(xl0+1)*68 + xc] = v.y;
    XsT[(xl0+2)*68 + xc] = v.z;
    XsT[(xl0+3)*68 + xc] = v.w;
    s16x4 xb;
    xb[0] = bf16b(v.x); xb[1] = bf16b(v.y); xb[2] = bf16b(v.z); xb[3] = bf16b(v.w);
    *(s16x4*)((ushort*)(out + SLAB(b, p, (xl0 >> 3))) + xc*8 + (xl0 & 4)) = xb;
  }
  *(float4*)(fws + t*4) = *(const float4*)(fw + t*4);
  if (t < 16) *(float4*)(fbs + t*4) = *(const float4*)(fb + t*4);
  bar_lds();  // B1

  // ---- P2a: G[l1][l2] ----
  {
    const int l1 = t >> 4, l2 = t & 15;
    const float* r1 = XsT + l1*68;
    const float* r2 = XsT + l2*68;
    float g = 0.f;
    #pragma unroll
    for (int cq = 0; cq < 16; ++cq) {
      const float4 a = *(const float4*)(r1 + cq*4);
      const float4 bb = *(const float4*)(r2 + cq*4);
      g += a.x*bb.x + a.y*bb.y + a.z*bb.z + a.w*bb.w;
    }
    Gs[t] = g;
  }
  // ---- P2b: Y = X*A ----
  {
    float4 acc4 = make_float4(0.f, 0.f, 0.f, 0.f);
    #pragma unroll
    for (int l = 0; l < 16; ++l) {
      const float xv = XsT[l*68 + xc];
      const float4 a = *(const float4*)(ws + WS_A + l*16 + xl0);
      acc4.x += xv*a.x; acc4.y += xv*a.y; acc4.z += xv*a.z; acc4.w += xv*a.w;
    }
    *(float4*)(Ys + xc*16 + xl0) = acc4;
  }
  // ---- P2c: wx + sincos -> GLOBAL rows 4..19 (register -> coalesced store) ----
  {
    const int c = t & 63, jb = t >> 6;
    float xr[16];
    #pragma unroll
    for (int l = 0; l < 16; ++l) xr[l] = XsT[l*68 + c];
    s16x8 ps[2], pc[2];
    #pragma unroll
    for (int jg = 0; jg < 4; ++jg) {
      const int j0 = jb*16 + jg*4;
      float4 wx4 = *(const float4*)(fbs + j0);
      #pragma unroll
      for (int l = 0; l < 16; ++l) {
        const float4 f = *(const float4*)(fws + l*64 + j0);
        wx4.x += xr[l]*f.x; wx4.y += xr[l]*f.y;
        wx4.z += xr[l]*f.z; wx4.w += xr[l]*f.w;
      }
      const int h = jg >> 1, e0 = (jg & 1) * 4;
      float sv, cv;
      __sincosf(wx4.x, &sv, &cv); ps[h][e0+0] = bf16b(sv); pc[h][e0+0] = bf16b(cv);
      __sincosf(wx4.y, &sv, &cv); ps[h][e0+1] = bf16b(sv); pc[h][e0+1] = bf16b(cv);
      __sincosf(wx4.z, &sv, &cv); ps[h][e0+2] = bf16b(sv); pc[h][e0+2] = bf16b(cv);
      __sincosf(wx4.w, &sv, &cv); ps[h][e0+3] = bf16b(sv); pc[h][e0+3] = bf16b(cv);
    }
    *(s16x8*)((ushort*)(out + SLAB(b, p,  4 + 2*jb)) + c*8) = ps[0];
    *(s16x8*)((ushort*)(out + SLAB(b, p,  5 + 2*jb)) + c*8) = ps[1];
    *(s16x8*)((ushort*)(out + SLAB(b, p, 12 + 2*jb)) + c*8) = pc[0];
    *(s16x8*)((ushort*)(out + SLAB(b, p, 13 + 2*jb)) + c*8) = pc[1];
  }
  bar_lds();  // B2

  // ---- P3: M = Y*G -> global rows 2-3 ; tls ----
  {
    float4 m = make_float4(0.f, 0.f, 0.f, 0.f);
    #pragma unroll
    for (int k = 0; k < 16; ++k) {
      const float yv = Ys[xc*16 + k];
      const float4 g = *(const float4*)(Gs + k*16 + xl0);
      m.x += yv*g.x; m.y += yv*g.y; m.z += yv*g.z; m.w += yv*g.w;
    }
    s16x4 mb;
    mb[0] = bf16b(m.x); mb[1] = bf16b(m.y); mb[2] = bf16b(m.z); mb[3] = bf16b(m.w);
    *(s16x4*)((ushort*)(out + SLAB(b, p, 2 + (xl0 >> 3))) + xc*8 + (xl0 & 4)) = mb;
  }
  if (t < 16) {
    float s = 0.f;
    #pragma unroll
    for (int q = 0; q < 4; ++q) {
      const float4 g = *(const float4*)(Gs + t*16 + q*4);
      const float4 wk = *(const float4*)(ws + WS_WK0 + q*4);
      s += g.x*wk.x + g.y*wk.y + g.z*wk.z + g.w*wk.w;
    }
    tls[t] = s;
  }
  bar_lds();  // B3

  // ---- P4: c0[d] -> global row 20 ----
  {
    float tl[16], e[16];
    #pragma unroll
    for (int q = 0; q < 4; ++q) {
      *(float4*)(tl + q*4) = *(const float4*)(tls + q*4);
      *(float4*)(e + q*4) = *(const float4*)(ws + WS_E0 + t*16 + q*4);
    }
    float s = pb[t];
    #pragma unroll
    for (int l = 0; l < 16; ++l) s += tl[l] * e[l];
    out[SLAB(b, p, 20) + t] = s;
  }
}

// ---------------- GEMM: LDS-free, reads acts+weights, writes all 64 rows ----------------
__global__ __launch_bounds__(256, 2)
void gemm_kernel(const float* __restrict__ ws, float* out)
{
  const int t = threadIdx.x;
  const int b = blockIdx.x >> 7;
  const int p = blockIdx.x & 127;
  const int lane = t & 63, w = t >> 6;
  const int n0 = w << 6;                    // wave's d-offset
  const int lr = lane & 15, lq = lane >> 4;
  const ushort* BTW = (const ushort*)(ws + WS_BT);

  f32x4 acc[4][4] = {};                     // [mi: d-tile][nt: c-tile]
  #pragma unroll
  for (int ks = 0; ks < 5; ++ks) {
    s16x8 af[4], bf_[4];
    #pragma unroll
    for (int mi = 0; mi < 4; ++mi)
      af[mi] = *(const s16x8*)&BTW[(n0 + mi*16 + lr)*160 + ks*32 + lq*8];
    #pragma unroll
    for (int nt = 0; nt < 4; ++nt)
      bf_[nt] = *(const s16x8*)((const ushort*)(out + SLAB(b, p, ks*4 + lq)) + (nt*16 + lr)*8);
    #pragma unroll
    for (int mi = 0; mi < 4; ++mi)
      #pragma unroll
      for (int nt = 0; nt < 4; ++nt)
        acc[mi][nt] = __builtin_amdgcn_mfma_f32_16x16x32_bf16(af[mi], bf_[nt], acc[mi][nt], 0, 0, 0);
  }

  // c0 from row 20
  float4 cv[4];
  #pragma unroll
  for (int mi = 0; mi < 4; ++mi)
    cv[mi] = *(const float4*)(out + SLAB(b, p, 20) + n0 + mi*16 + (lq << 2));

  // RACE FIX: all waves' slab reads must land before ANY wave's epilogue
  // stores overwrite rows c=0..20. __syncthreads drains vmcnt(0) before
  // s_barrier (compiler-enforced), giving exactly that guarantee.
  __syncthreads();

  // epilogue: lane holds 4 consecutive d -> 16 float4 stores (64B segments)
  #pragma unroll
  for (int nt = 0; nt < 4; ++nt) {
    const int c = nt*16 + lr;
    float* rp = out + (((b*64 + c)*128 + p) << 8) + n0 + (lq << 2);
    #pragma unroll
    for (int mi = 0; mi < 4; ++mi) {
      float4 o;
      o.x = acc[mi][nt][0] + cv[mi].x;
      o.y = acc[mi][nt][1] + cv[mi].y;
      o.z = acc[mi][nt][2] + cv[mi].z;
      o.w = acc[mi][nt][3] + cv[mi].w;
      *(float4*)(rp + mi*16) = o;
    }
  }
}

extern "C" void kernel_launch(void* const* d_in, const int* in_sizes, int n_in,
                              void* d_out, int out_size, void* d_ws, size_t ws_size,
                              hipStream_t stream) {
  const float* x  = (const float*)d_in[0];
  const float* Wq = (const float*)d_in[1];
  const float* Wk = (const float*)d_in[2];
  const float* Wv = (const float*)d_in[3];
  const float* fw = (const float*)d_in[4];
  const float* fb = (const float*)d_in[5];
  const float* pw = (const float*)d_in[6];
  const float* pb = (const float*)d_in[7];
  float* out = (float*)d_out;
  float* ws  = (float*)d_ws;   // needs 24848 floats ~ 100 KB

  pre_kernel<<<18, 512, 0, stream>>>(Wq, Wk, Wv, pw, ws);
  acts_kernel<<<16*128, 256, 0, stream>>>(x, fw, fb, pb, ws, out);
  gemm_kernel<<<16*128, 256, 0, stream>>>(ws, out);
}

// Round 10
// 66.149 us; speedup vs baseline: 1.1849x; 1.1849x over previous
//
#include <hip/hip_runtime.h>
#include <hip/hip_bf16.h>

// B=16, C=64, P=128, L=16, D=256, NPF=256, NRFF=128, FEAT=656
// ws layout (float slots):
#define WS_WK0   0        // 16     wk0 = Wk0^T q0
#define WS_A     16       // 256    A = Wq1^T Wk1
#define WS_E0    272      // 4096   E0 = Pp0 * Wv0  (256 x 16), f32 (for c0)
#define WS_BT    4368     // 20480 f32-slots = 40960 ushort: BTall[256][160] bf16
//   BTall[d][kk]: 0..15 Px; 16..31 E1; 32..95 Psin; 96..159 Pcos

typedef float f32x4 __attribute__((ext_vector_type(4)));
typedef short s16x8 __attribute__((ext_vector_type(8)));
typedef short s16x4 __attribute__((ext_vector_type(4)));

static __device__ __forceinline__ short bf16b(float f) {
  __hip_bfloat16 h = __float2bfloat16(f);
  return __builtin_bit_cast(short, h);
}

// lgkmcnt-only barrier: orders LDS producer->consumer without draining vmcnt,
// so global stores / prefetches stay in flight across phases.
static __device__ __forceinline__ void bar_lds() {
  asm volatile("s_waitcnt lgkmcnt(0)\n\ts_barrier" ::: "memory");
}

__global__ __launch_bounds__(512)
void pre_kernel(const float* __restrict__ Wq, const float* __restrict__ Wk,
                const float* __restrict__ Wv, const float* __restrict__ pw,
                float* __restrict__ ws)
{
  __shared__ float lds[8704];
  const int t = threadIdx.x;
  const int blk = blockIdx.x;
  ushort* bt = (ushort*)(ws + WS_BT);

  if (blk == 0) {
    {
      const int d = t >> 1;
      const int lb = (t & 1) * 8;
      #pragma unroll
      for (int h = 0; h < 2; ++h) {
        const float4 vq = *(const float4*)(Wq + 4096 + t*8 + h*4);
        lds[(lb+h*4+0)*256 + d] = vq.x;
        lds[(lb+h*4+1)*256 + d] = vq.y;
        lds[(lb+h*4+2)*256 + d] = vq.z;
        lds[(lb+h*4+3)*256 + d] = vq.w;
        const float4 vk = *(const float4*)(Wk + 4096 + t*8 + h*4);
        lds[4096 + (lb+h*4+0)*256 + d] = vk.x;
        lds[4096 + (lb+h*4+1)*256 + d] = vk.y;
        lds[4096 + (lb+h*4+2)*256 + d] = vk.z;
        lds[4096 + (lb+h*4+3)*256 + d] = vk.w;
      }
    }
    if (t < 256) {
      float s = 0.f;
      #pragma unroll
      for (int q = 0; q < 4; ++q) {
        const float4 v = *(const float4*)(Wq + t*16 + q*4);
        s += v.x + v.y + v.z + v.w;           // q0[d]
      }
      lds[8192 + t] = s;
    }
    __syncthreads();
    if (t < 256) {
      const int l1 = t >> 4, l2 = t & 15;
      const float* r1 = lds + l1*256;
      const float* r2 = lds + 4096 + l2*256;
      float s = 0.f;
      #pragma unroll 8
      for (int dq = 0; dq < 64; ++dq) {
        const float4 a = *(const float4*)(r1 + dq*4);
        const float4 b = *(const float4*)(r2 + dq*4);
        s += a.x*b.x + a.y*b.y + a.z*b.z + a.w*b.w;    // A[l1,l2]
      }
      ws[WS_A + t] = s;
    }
    if (t < 256) {                 // wk0 partial sums, parallel over d-chunks
      const int l = t & 15, ch = t >> 4;
      float s = 0.f;
      #pragma unroll
      for (int i = 0; i < 16; ++i)
        s += lds[8192 + ch*16 + i] * Wk[(ch*16 + i)*16 + l];
      lds[8448 + t] = s;
    }
    __syncthreads();
    if (t < 16) {
      float s = 0.f;
      #pragma unroll
      for (int ch = 0; ch < 16; ++ch) s += lds[8448 + ch*16 + t];
      ws[WS_WK0 + t] = s;          // wk0[l]
    }
  } else if (blk <= 16) {
    const int deg = (blk <= 8) ? 0 : 1;
    {
      const int f = t >> 1;
      const int lb = (t & 1) * 8;
      #pragma unroll
      for (int h = 0; h < 2; ++h) {
        const float4 v = *(const float4*)(Wv + deg*4096 + t*8 + h*4);
        lds[(lb+h*4+0)*256 + f] = v.x;
        lds[(lb+h*4+1)*256 + f] = v.y;
        lds[(lb+h*4+2)*256 + f] = v.z;
        lds[(lb+h*4+3)*256 + f] = v.w;
      }
    }
    __syncthreads();
    const int d = ((blk-1) & 7)*32 + (t >> 4);
    const int l = t & 15;
    const float* pr = pw + d*656 + (deg ? 272 : 16);
    const float* wv = lds + l*256;
    float s = 0.f;
    #pragma unroll 8
    for (int fq = 0; fq < 64; ++fq) {
      const float4 a = *(const float4*)(pr + fq*4);
      const float4 b = *(const float4*)(wv + fq*4);
      s += a.x*b.x + a.y*b.y + a.z*b.z + a.w*b.w;
    }
    if (deg == 0) {
      ws[WS_E0 + d*16 + l] = s;
      bt[d*160 + l] = (ushort)bf16b(pw[d*656 + l]);
    } else {
      bt[d*160 + 16 + l] = (ushort)bf16b(s);
    }
  } else {
    #pragma unroll 4
    for (int k = 0; k < 64; ++k) {
      const int d = k*4 + (t >> 7);
      const int j = t & 127;
      const float v = (j < 64) ? pw[d*656 + 528 + j] : pw[d*656 + 592 + (j-64)];
      bt[d*160 + 32 + j] = (ushort)bf16b(v);
    }
  }
}

// One block per (b, p, d-half): acts computed per block (cheap, VALU was idle),
// MFMA + stores over 128 of the 256 d's. 4096 blocks -> 16 seq/CU, ~5 resident.
__global__ __launch_bounds__(256, 2)
void main_kernel(const float* __restrict__ x, const float* __restrict__ fw,
                 const float* __restrict__ fb, const float* __restrict__ pw,
                 const float* __restrict__ pb, const float* __restrict__ ws,
                 float* __restrict__ out)
{
  __shared__ float XsT[16*68];   // f32 x^T [l][c]
  __shared__ float fws[16*64];
  __shared__ float fbs[64];
  __shared__ float Gs[256];      // G = X^T X
  __shared__ float AGs[256];     // AG = A * G  (16x16)
  __shared__ float tls[16];      // G * wk0
  __shared__ float c0s[256];     // pb + E0 * tls
  __shared__ short Abf[20*64*8]; // bf16 acts [kt][c][8]: kt0-1=x, kt2-3=M, kt4-11=sin, kt12-19=cos
  // total ~31.6 KB -> ~5 blocks/CU

  const int t = threadIdx.x;
  const int b  = blockIdx.x >> 8;
  const int p  = (blockIdx.x >> 1) & 127;
  const int dh = blockIdx.x & 1;

  const int lane = t & 63, w = t >> 6;
  const int n0 = dh*128 + w*32;             // wave's d-offset (32 wide)
  const int lr = lane & 15, lq = lane >> 4;
  const int xc = t >> 2, xl0 = (t & 3) * 4;
  const ushort* BTW = (const ushort*)(ws + WS_BT);

  // ---- P1: stage X (f32 + bf16 kt0-1), fw, fb ----
  {
    const float4 v = *(const float4*)(x + (((b*64 + xc)*128 + p) << 4) + xl0);
    XsT[(xl0+0)*68 + xc] = v.x;
    XsT[(xl0+1)*68 + xc] = v.y;
    XsT[(xl0+2)*68 + xc] = v.z;
    XsT[(xl0+3)*68 + xc] = v.w;
    s16x4 xb;
    xb[0] = bf16b(v.x); xb[1] = bf16b(v.y); xb[2] = bf16b(v.z); xb[3] = bf16b(v.w);
    *(s16x4*)&Abf[(((xl0>>3)*64 + xc) << 3) + (xl0 & 4)] = xb;
  }
  *(float4*)(fws + t*4) = *(const float4*)(fw + t*4);
  if (t < 16) *(float4*)(fbs + t*4) = *(const float4*)(fb + t*4);
  bar_lds();  // B1

  // ---- P2a: G[l1][l2] (float4) ----
  {
    const int l1 = t >> 4, l2 = t & 15;
    const float* r1 = XsT + l1*68;
    const float* r2 = XsT + l2*68;
    float g = 0.f;
    #pragma unroll
    for (int cq = 0; cq < 16; ++cq) {
      const float4 a = *(const float4*)(r1 + cq*4);
      const float4 bb = *(const float4*)(r2 + cq*4);
      g += a.x*bb.x + a.y*bb.y + a.z*bb.z + a.w*bb.w;
    }
    Gs[t] = g;
  }
  // ---- P2b: wx + sincos -> Abf kt4..19 ----
  {
    const int c = t & 63, jb = t >> 6;
    float xr[16];
    #pragma unroll
    for (int l = 0; l < 16; ++l) xr[l] = XsT[l*68 + c];
    s16x8 ps[2], pc[2];
    #pragma unroll
    for (int jg = 0; jg < 4; ++jg) {
      const int j0 = jb*16 + jg*4;
      float4 wx4 = *(const float4*)(fbs + j0);
      #pragma unroll
      for (int l = 0; l < 16; ++l) {
        const float4 f = *(const float4*)(fws + l*64 + j0);
        wx4.x += xr[l]*f.x; wx4.y += xr[l]*f.y;
        wx4.z += xr[l]*f.z; wx4.w += xr[l]*f.w;
      }
      const int h = jg >> 1, e0 = (jg & 1) * 4;
      float sv, cv;
      __sincosf(wx4.x, &sv, &cv); ps[h][e0+0] = bf16b(sv); pc[h][e0+0] = bf16b(cv);
      __sincosf(wx4.y, &sv, &cv); ps[h][e0+1] = bf16b(sv); pc[h][e0+1] = bf16b(cv);
      __sincosf(wx4.z, &sv, &cv); ps[h][e0+2] = bf16b(sv); pc[h][e0+2] = bf16b(cv);
      __sincosf(wx4.w, &sv, &cv); ps[h][e0+3] = bf16b(sv); pc[h][e0+3] = bf16b(cv);
    }
    *(s16x8*)&Abf[(((4 + 2*jb)*64 + c) << 3)] = ps[0];
    *(s16x8*)&Abf[(((5 + 2*jb)*64 + c) << 3)] = ps[1];
    *(s16x8*)&Abf[(((12 + 2*jb)*64 + c) << 3)] = pc[0];
    *(s16x8*)&Abf[(((13 + 2*jb)*64 + c) << 3)] = pc[1];
  }
  bar_lds();  // B2

  // ---- P3: AG = A*G (16x16); tls = G*wk0 ----
  {
    const int l = t >> 4, lp = t & 15;
    float a[16];
    #pragma unroll
    for (int q = 0; q < 4; ++q)
      *(float4*)(a + q*4) = *(const float4*)(ws + WS_A + l*16 + q*4);
    float s = 0.f;
    #pragma unroll
    for (int k = 0; k < 16; ++k) s += a[k] * Gs[k*16 + lp];
    AGs[t] = s;
  }
  if (t < 16) {
    float s = 0.f;
    #pragma unroll
    for (int q = 0; q < 4; ++q) {
      const float4 g = *(const float4*)(Gs + t*16 + q*4);
      const float4 wk = *(const float4*)(ws + WS_WK0 + q*4);
      s += g.x*wk.x + g.y*wk.y + g.z*wk.z + g.w*wk.w;
    }
    tls[t] = s;
  }
  bar_lds();  // B3

  // ---- P4: M = X*AG -> Abf kt2-3 ; c0s ----
  {
    float4 m = make_float4(0.f, 0.f, 0.f, 0.f);
    #pragma unroll
    for (int l = 0; l < 16; ++l) {
      const float xv = XsT[l*68 + xc];
      const float4 g = *(const float4*)(AGs + l*16 + xl0);
      m.x += xv*g.x; m.y += xv*g.y; m.z += xv*g.z; m.w += xv*g.w;
    }
    s16x4 mb;
    mb[0] = bf16b(m.x); mb[1] = bf16b(m.y); mb[2] = bf16b(m.z); mb[3] = bf16b(m.w);
    *(s16x4*)&Abf[(((2 + (xl0>>3))*64 + xc) << 3) + (xl0 & 4)] = mb;
  }
  {
    float tl[16], e[16];
    #pragma unroll
    for (int q = 0; q < 4; ++q) {
      *(float4*)(tl + q*4) = *(const float4*)(tls + q*4);
      *(float4*)(e + q*4) = *(const float4*)(ws + WS_E0 + t*16 + q*4);
    }
    float s = pb[t];
    #pragma unroll
    for (int l = 0; l < 16; ++l) s += tl[l] * e[l];
    c0s[t] = s;
  }
  bar_lds();  // B4

  // ---- P5: MFMA, A = acts (rows c), B = weights (this block's 128 d's) ----
  f32x4 acc[4][2] = {};                  // [mi: c-tile][nt: d-tile]
  #pragma unroll
  for (int ks = 0; ks < 5; ++ks) {
    s16x8 af[4], bf_[2];
    #pragma unroll
    for (int mi = 0; mi < 4; ++mi)
      af[mi] = *(const s16x8*)&Abf[(((ks*4 + lq)*64) + mi*16 + lr) << 3];
    #pragma unroll
    for (int nt = 0; nt < 2; ++nt)
      bf_[nt] = *(const s16x8*)&BTW[(n0 + nt*16 + lr)*160 + ks*32 + lq*8];
    #pragma unroll
    for (int mi = 0; mi < 4; ++mi)
      #pragma unroll
      for (int nt = 0; nt < 2; ++nt)
        acc[mi][nt] = __builtin_amdgcn_mfma_f32_16x16x32_bf16(af[mi], bf_[nt], acc[mi][nt], 0, 0, 0);
  }

  // ---- epilogue: adjacent lanes -> adjacent d (64B segments) ----
  #pragma unroll
  for (int nt = 0; nt < 2; ++nt) {
    const int d = n0 + nt*16 + lr;
    const float cc = c0s[d];
    #pragma unroll
    for (int mi = 0; mi < 4; ++mi) {
      #pragma unroll
      for (int r = 0; r < 4; ++r) {
        const int c = mi*16 + lq*4 + r;
        out[(((b*64 + c)*128 + p) << 8) + d] = acc[mi][nt][r] + cc;
      }
    }
  }
}

extern "C" void kernel_launch(void* const* d_in, const int* in_sizes, int n_in,
                              void* d_out, int out_size, void* d_ws, size_t ws_size,
                              hipStream_t stream) {
  const float* x  = (const float*)d_in[0];
  const float* Wq = (const float*)d_in[1];
  const float* Wk = (const float*)d_in[2];
  const float* Wv = (const float*)d_in[3];
  const float* fw = (const float*)d_in[4];
  const float* fb = (const float*)d_in[5];
  const float* pw = (const float*)d_in[6];
  const float* pb = (const float*)d_in[7];
  float* out = (float*)d_out;
  float* ws  = (float*)d_ws;   // needs 24848 floats ~ 100 KB

  pre_kernel<<<18, 512, 0, stream>>>(Wq, Wk, Wv, pw, ws);
  main_kernel<<<16*128*2, 256, 0, stream>>>(x, fw, fb, pw, pb, ws, out);
}

// Round 11
// 51.791 us; speedup vs baseline: 1.5135x; 1.2772x over previous
//
#include <hip/hip_runtime.h>
#include <hip/hip_bf16.h>

// B=16, C=64, P=128, L=16, D=256, NPF=256, NRFF=128, FEAT=656
// ws layout (float slots):
#define WS_WK0   0        // 16     wk0 = Wk0^T q0
#define WS_A     16       // 256    A = Wq1^T Wk1
#define WS_E0    272      // 4096   E0 = Pp0 * Wv0  (256 x 16), f32 (for c0)
#define WS_BT    4368     // 20480 f32-slots = 40960 ushort: BTall[256][160] bf16
//   BTall[d][kk]: 0..15 Px; 16..31 E1; 32..95 Psin; 96..159 Pcos

typedef float f32x4 __attribute__((ext_vector_type(4)));
typedef short s16x8 __attribute__((ext_vector_type(8)));
typedef short s16x4 __attribute__((ext_vector_type(4)));

static __device__ __forceinline__ short bf16b(float f) {
  __hip_bfloat16 h = __float2bfloat16(f);
  return __builtin_bit_cast(short, h);
}
static __device__ __forceinline__ float bf2f(short s) {
  unsigned u = ((unsigned)(unsigned short)s) << 16;
  return __builtin_bit_cast(float, u);
}

// lgkmcnt-only barrier: orders LDS producer->consumer without draining vmcnt.
static __device__ __forceinline__ void bar_lds() {
  asm volatile("s_waitcnt lgkmcnt(0)\n\ts_barrier" ::: "memory");
}

__global__ __launch_bounds__(512)
void pre_kernel(const float* __restrict__ Wq, const float* __restrict__ Wk,
                const float* __restrict__ Wv, const float* __restrict__ pw,
                float* __restrict__ ws)
{
  __shared__ float lds[8704];
  const int t = threadIdx.x;
  const int blk = blockIdx.x;
  ushort* bt = (ushort*)(ws + WS_BT);

  if (blk == 0) {
    {
      const int d = t >> 1;
      const int lb = (t & 1) * 8;
      #pragma unroll
      for (int h = 0; h < 2; ++h) {
        const float4 vq = *(const float4*)(Wq + 4096 + t*8 + h*4);
        lds[(lb+h*4+0)*256 + d] = vq.x;
        lds[(lb+h*4+1)*256 + d] = vq.y;
        lds[(lb+h*4+2)*256 + d] = vq.z;
        lds[(lb+h*4+3)*256 + d] = vq.w;
        const float4 vk = *(const float4*)(Wk + 4096 + t*8 + h*4);
        lds[4096 + (lb+h*4+0)*256 + d] = vk.x;
        lds[4096 + (lb+h*4+1)*256 + d] = vk.y;
        lds[4096 + (lb+h*4+2)*256 + d] = vk.z;
        lds[4096 + (lb+h*4+3)*256 + d] = vk.w;
      }
    }
    if (t < 256) {
      float s = 0.f;
      #pragma unroll
      for (int q = 0; q < 4; ++q) {
        const float4 v = *(const float4*)(Wq + t*16 + q*4);
        s += v.x + v.y + v.z + v.w;           // q0[d]
      }
      lds[8192 + t] = s;
    }
    __syncthreads();
    if (t < 256) {
      const int l1 = t >> 4, l2 = t & 15;
      const float* r1 = lds + l1*256;
      const float* r2 = lds + 4096 + l2*256;
      float s = 0.f;
      #pragma unroll 8
      for (int dq = 0; dq < 64; ++dq) {
        const float4 a = *(const float4*)(r1 + dq*4);
        const float4 b = *(const float4*)(r2 + dq*4);
        s += a.x*b.x + a.y*b.y + a.z*b.z + a.w*b.w;    // A[l1,l2]
      }
      ws[WS_A + t] = s;
    }
    if (t < 256) {                 // wk0 partial sums
      const int l = t & 15, ch = t >> 4;
      float s = 0.f;
      #pragma unroll
      for (int i = 0; i < 16; ++i)
        s += lds[8192 + ch*16 + i] * Wk[(ch*16 + i)*16 + l];
      lds[8448 + t] = s;
    }
    __syncthreads();
    if (t < 16) {
      float s = 0.f;
      #pragma unroll
      for (int ch = 0; ch < 16; ++ch) s += lds[8448 + ch*16 + t];
      ws[WS_WK0 + t] = s;          // wk0[l]
    }
  } else if (blk <= 16) {
    const int deg = (blk <= 8) ? 0 : 1;
    {
      const int f = t >> 1;
      const int lb = (t & 1) * 8;
      #pragma unroll
      for (int h = 0; h < 2; ++h) {
        const float4 v = *(const float4*)(Wv + deg*4096 + t*8 + h*4);
        lds[(lb+h*4+0)*256 + f] = v.x;
        lds[(lb+h*4+1)*256 + f] = v.y;
        lds[(lb+h*4+2)*256 + f] = v.z;
        lds[(lb+h*4+3)*256 + f] = v.w;
      }
    }
    __syncthreads();
    const int d = ((blk-1) & 7)*32 + (t >> 4);
    const int l = t & 15;
    const float* pr = pw + d*656 + (deg ? 272 : 16);
    const float* wv = lds + l*256;
    float s = 0.f;
    #pragma unroll 8
    for (int fq = 0; fq < 64; ++fq) {
      const float4 a = *(const float4*)(pr + fq*4);
      const float4 b = *(const float4*)(wv + fq*4);
      s += a.x*b.x + a.y*b.y + a.z*b.z + a.w*b.w;
    }
    if (deg == 0) {
      ws[WS_E0 + d*16 + l] = s;
      bt[d*160 + l] = (ushort)bf16b(pw[d*656 + l]);
    } else {
      bt[d*160 + 16 + l] = (ushort)bf16b(s);
    }
  } else {
    #pragma unroll 4
    for (int k = 0; k < 64; ++k) {
      const int d = k*4 + (t >> 7);
      const int j = t & 127;
      const float v = (j < 64) ? pw[d*656 + 528 + j] : pw[d*656 + 592 + (j-64)];
      bt[d*160 + 32 + j] = (ushort)bf16b(v);
    }
  }
}

__global__ __launch_bounds__(256, 2)
void main_kernel(const float* __restrict__ x, const float* __restrict__ fw,
                 const float* __restrict__ fb, const float* __restrict__ pb,
                 const float* __restrict__ ws, float* __restrict__ out)
{
  __shared__ short Xb[64*40];    // bf16 X [c][k], 80B rows; k<16 = x, k in [16,32) = 0
  __shared__ short XbT[16*72];   // bf16 X^T [l][c], 144B rows (conflict-padded)
  __shared__ short Fwt[64*40];   // bf16 fw^T [j][k], 80B rows; k<16 = fw[k][j], else 0
  __shared__ float fbs[64];
  __shared__ float Gs[256];      // G = X^T X (f32, from MFMA)
  __shared__ float AGs[256];     // AG = A * G
  __shared__ float tls[16];      // G * wk0
  __shared__ float c0s[256];     // pb + E0 * tls
  __shared__ short Abf[20*64*8]; // bf16 acts [kt][c][8]: kt0-1=x, kt2-3=M, kt4-11=sin, kt12-19=cos
  // ~35.6 KB

  const int t = threadIdx.x;
  const int b = blockIdx.x >> 7;
  const int p = blockIdx.x & 127;

  const int lane = t & 63, w = t >> 6;
  const int n0 = w << 6;                    // wave's d-offset
  const int lr = lane & 15, lq = lane >> 4;
  const int xc = t >> 2, xl0 = (t & 3) * 4;
  const ushort* BTW = (const ushort*)(ws + WS_BT);

  // ---- P1: stage X (3 bf16 layouts) + fw^T + fb ----
  {
    const float4 v = *(const float4*)(x + (((b*64 + xc)*128 + p) << 4) + xl0);
    s16x4 xb;
    xb[0] = bf16b(v.x); xb[1] = bf16b(v.y); xb[2] = bf16b(v.z); xb[3] = bf16b(v.w);
    s16x4 z; z[0] = 0; z[1] = 0; z[2] = 0; z[3] = 0;
    *(s16x4*)&Xb[xc*40 + xl0] = xb;
    *(s16x4*)&Xb[xc*40 + 16 + xl0] = z;            // zero-pad k 16..31
    XbT[(xl0+0)*72 + xc] = xb[0];
    XbT[(xl0+1)*72 + xc] = xb[1];
    XbT[(xl0+2)*72 + xc] = xb[2];
    XbT[(xl0+3)*72 + xc] = xb[3];
    *(s16x4*)&Abf[(((xl0>>3)*64 + xc) << 3) + (xl0 & 4)] = xb;
    // fw^T: thread covers fw row l = t>>4, cols j0..j0+3
    const int l = t >> 4, j0 = (t & 15) * 4;
    const float4 f = *(const float4*)(fw + l*64 + j0);
    Fwt[(j0+0)*40 + l] = (short)bf16b(f.x);
    Fwt[(j0+1)*40 + l] = (short)bf16b(f.y);
    Fwt[(j0+2)*40 + l] = (short)bf16b(f.z);
    Fwt[(j0+3)*40 + l] = (short)bf16b(f.w);
    *(s16x4*)&Fwt[(t>>2)*40 + 16 + (t & 3)*4] = z; // zero-pad k 16..31
    if (t < 16) *(float4*)(fbs + t*4) = *(const float4*)(fb + t*4);
  }
  bar_lds();  // B1

  // ---- P2a (wave 0): G = X^T X via MFMA, A = B = XbT fragment ----
  if (w == 0) {
    f32x4 g = {};
    #pragma unroll
    for (int ks = 0; ks < 2; ++ks) {
      const s16x8 xa = *(const s16x8*)&XbT[lr*72 + ks*32 + lq*8];
      g = __builtin_amdgcn_mfma_f32_16x16x32_bf16(xa, xa, g, 0, 0, 0);
    }
    #pragma unroll
    for (int r = 0; r < 4; ++r) Gs[(lq*4 + r)*16 + lr] = g[r];   // row=lq*4+r, col=lr
  }
  // ---- P2b (all waves): wx = X*fw via MFMA; j-block = w; then sincos -> Abf ----
  {
    s16x8 xa[4];
    #pragma unroll
    for (int mi = 0; mi < 4; ++mi)
      xa[mi] = *(const s16x8*)&Xb[(mi*16 + lr)*40 + lq*8];
    const s16x8 fwf = *(const s16x8*)&Fwt[(w*16 + lr)*40 + lq*8];
    f32x4 wa[4];
    #pragma unroll
    for (int mi = 0; mi < 4; ++mi) {
      f32x4 zz = {};
      wa[mi] = __builtin_amdgcn_mfma_f32_16x16x32_bf16(xa[mi], fwf, zz, 0, 0, 0);
    }
    const float fbj = fbs[w*16 + lr];          // lane's j = w*16 + lr
    const int ktS = 4 + 2*w + (lr >> 3);       // sin row: 4 + j/8
    const int ktC = ktS + 8;                   // cos row
    const int e = lr & 7;                      // j % 8
    #pragma unroll
    for (int mi = 0; mi < 4; ++mi) {
      #pragma unroll
      for (int r = 0; r < 4; ++r) {
        const int c = mi*16 + lq*4 + r;        // D row = c
        float sv, cv;
        __sincosf(wa[mi][r] + fbj, &sv, &cv);
        Abf[(ktS*64 + c)*8 + e] = bf16b(sv);
        Abf[(ktC*64 + c)*8 + e] = bf16b(cv);
      }
    }
  }
  bar_lds();  // B2

  // ---- P3: AG = A*G (VALU, small); tls = G*wk0 ----
  {
    const int l = t >> 4, lp = t & 15;
    float a[16];
    #pragma unroll
    for (int q = 0; q < 4; ++q)
      *(float4*)(a + q*4) = *(const float4*)(ws + WS_A + l*16 + q*4);
    float s = 0.f;
    #pragma unroll
    for (int k = 0; k < 16; ++k) s += a[k] * Gs[k*16 + lp];
    AGs[t] = s;
  }
  if (t < 16) {
    float s = 0.f;
    #pragma unroll
    for (int q = 0; q < 4; ++q) {
      const float4 g = *(const float4*)(Gs + t*16 + q*4);
      const float4 wk = *(const float4*)(ws + WS_WK0 + q*4);
      s += g.x*wk.x + g.y*wk.y + g.z*wk.z + g.w*wk.w;
    }
    tls[t] = s;
  }
  bar_lds();  // B3

  // ---- P4: M = X*AG -> Abf kt2-3 ; c0s ----
  {
    const s16x8 xlo = *(const s16x8*)&Xb[xc*40];
    const s16x8 xhi = *(const s16x8*)&Xb[xc*40 + 8];
    float4 m = make_float4(0.f, 0.f, 0.f, 0.f);
    #pragma unroll
    for (int i = 0; i < 8; ++i) {
      const float xv = bf2f(xlo[i]);
      const float4 g = *(const float4*)(AGs + i*16 + xl0);
      m.x += xv*g.x; m.y += xv*g.y; m.z += xv*g.z; m.w += xv*g.w;
    }
    #pragma unroll
    for (int i = 0; i < 8; ++i) {
      const float xv = bf2f(xhi[i]);
      const float4 g = *(const float4*)(AGs + (8+i)*16 + xl0);
      m.x += xv*g.x; m.y += xv*g.y; m.z += xv*g.z; m.w += xv*g.w;
    }
    s16x4 mb;
    mb[0] = bf16b(m.x); mb[1] = bf16b(m.y); mb[2] = bf16b(m.z); mb[3] = bf16b(m.w);
    *(s16x4*)&Abf[(((2 + (xl0>>3))*64 + xc) << 3) + (xl0 & 4)] = mb;
  }
  {
    float tl[16], e[16];
    #pragma unroll
    for (int q = 0; q < 4; ++q) {
      *(float4*)(tl + q*4) = *(const float4*)(tls + q*4);
      *(float4*)(e + q*4) = *(const float4*)(ws + WS_E0 + t*16 + q*4);
    }
    float s = pb[t];
    #pragma unroll
    for (int l = 0; l < 16; ++l) s += tl[l] * e[l];
    c0s[t] = s;
  }
  bar_lds();  // B4

  // ---- P5: big MFMA, A = acts (rows c), B = weights (cols d); K = 160 ----
  f32x4 acc[4][4] = {};                  // [mi: c-tile][nt: d-tile]
  #pragma unroll
  for (int ks = 0; ks < 5; ++ks) {
    s16x8 af[4], bf_[4];
    #pragma unroll
    for (int mi = 0; mi < 4; ++mi)
      af[mi] = *(const s16x8*)&Abf[(((ks*4 + lq)*64) + mi*16 + lr) << 3];
    #pragma unroll
    for (int nt = 0; nt < 4; ++nt)
      bf_[nt] = *(const s16x8*)&BTW[(n0 + nt*16 + lr)*160 + ks*32 + lq*8];
    #pragma unroll
    for (int mi = 0; mi < 4; ++mi)
      #pragma unroll
      for (int nt = 0; nt < 4; ++nt)
        acc[mi][nt] = __builtin_amdgcn_mfma_f32_16x16x32_bf16(af[mi], bf_[nt], acc[mi][nt], 0, 0, 0);
  }

  // ---- epilogue: D col = d (adjacent lanes -> adjacent d, 64B segments) ----
  #pragma unroll
  for (int nt = 0; nt < 4; ++nt) {
    const int d = n0 + nt*16 + lr;
    const float cc = c0s[d];
    #pragma unroll
    for (int mi = 0; mi < 4; ++mi) {
      #pragma unroll
      for (int r = 0; r < 4; ++r) {
        const int c = mi*16 + lq*4 + r;
        out[(((b*64 + c)*128 + p) << 8) + d] = acc[mi][nt][r] + cc;
      }
    }
  }
}

extern "C" void kernel_launch(void* const* d_in, const int* in_sizes, int n_in,
                              void* d_out, int out_size, void* d_ws, size_t ws_size,
                              hipStream_t stream) {
  const float* x  = (const float*)d_in[0];
  const float* Wq = (const float*)d_in[1];
  const float* Wk = (const float*)d_in[2];
  const float* Wv = (const float*)d_in[3];
  const float* fw = (const float*)d_in[4];
  const float* fb = (const float*)d_in[5];
  const float* pw = (const float*)d_in[6];
  const float* pb = (const float*)d_in[7];
  float* out = (float*)d_out;
  float* ws  = (float*)d_ws;   // needs 24848 floats ~ 100 KB

  pre_kernel<<<18, 512, 0, stream>>>(Wq, Wk, Wv, pw, ws);
  main_kernel<<<16*128, 256, 0, stream>>>(x, fw, fb, pb, ws, out);
}